// Round 6
// baseline (31.945 us; speedup 1.0000x reference)
//
#include <hip/hip_runtime.h>

// Problem constants (from reference): B=8, T=4096, LZ=1024, D=1024
#define B_N   8
#define T_N   4096
#define LZ_N  1024
#define D_N   1024
#define ROWS_TOTAL (B_N * T_N)            // 32768
#define NBLK  1024                        // blocks (divisible by 8 for XCD swizzle)
#define ROWS_PER_BLK (ROWS_TOTAL / NBLK)  // 32 contiguous rows per block

typedef float fx4 __attribute__((ext_vector_type(4)));

// ---------------------------------------------------------------------------
// Fused kernel: each block handles 32 contiguous output rows [base, base+32).
// Preamble: block recomputes the exclusive cumsum of b[batch][0..base+32)
//   itself (<=16 ints/thread, wave-shfl scan) and stashes the 33 needed
//   clipped idx values + 32 p coefs in LDS. b is 16KB/batch -> L2-resident.
// Main loop: BRANCH-FREE — one unconditional z load per row; repeats of the
//   same z row are L1 hits. v_prev carried in registers. Nontemporal stores.
// XCD-bijective swizzle: each XCD covers exactly one batch -> z working set
//   per XCD = 4MB = its private L2.
// ---------------------------------------------------------------------------
__global__ __launch_bounds__(256) void fused_kernel(const float* __restrict__ z,
                                                    const float* __restrict__ p,
                                                    const int* __restrict__ b,
                                                    float* __restrict__ out) {
    const int bid   = blockIdx.x;
    const int swz   = (bid & 7) * (NBLK / 8) + (bid >> 3);
    const int base  = swz * ROWS_PER_BLK;         // first row of this chunk
    const int batch = base >> 12;                 // T_N = 4096
    const int t0    = base & (T_N - 1);           // multiple of 32
    const int tid   = threadIdx.x;
    const int lane  = tid & 63;
    const int wid   = tid >> 6;
    const int last_chunk = t0 >> 4;               // chunk holding rows base..base+15
    const int nchunk     = last_chunk + 2;        // chunks covering [0, base+32)

    const int* bb = b + (size_t)batch * T_N;

    // --- per-thread chunk load + sum (only threads < nchunk do real work) ---
    int vals[16];
    int lsum = 0;
    if (tid < nchunk) {
        const int4* b4 = (const int4*)(bb + tid * 16);
#pragma unroll
        for (int j = 0; j < 4; ++j) {
            int4 v = b4[j];
            vals[4 * j + 0] = v.x;
            vals[4 * j + 1] = v.y;
            vals[4 * j + 2] = v.z;
            vals[4 * j + 3] = v.w;
        }
#pragma unroll
        for (int j = 0; j < 16; ++j) lsum += vals[j];
    }

    // --- inclusive scan over the 256 per-thread sums: shfl within wave, then
    //     combine the 4 wave totals once through LDS ---
    int s = lsum;
#pragma unroll
    for (int off = 1; off < 64; off <<= 1) {
        int n = __shfl_up(s, off, 64);
        if (lane >= off) s += n;
    }
    __shared__ int   wsum[4];
    __shared__ int   sh_idx[ROWS_PER_BLK + 1];
    __shared__ float sh_p[ROWS_PER_BLK];
    if (lane == 63) wsum[wid] = s;
    __syncthreads();
    int wbase = 0;
#pragma unroll
    for (int w = 0; w < 3; ++w) if (w < wid) wbase += wsum[w];
    const int incl  = s + wbase;    // inclusive cumsum of chunk sums through tid
    const int exclc = incl - lsum;  // exclusive cumsum at this chunk's start

    // --- owner threads emit idx[base..base+31]; neighbor emits idx[base-1] ---
    if (tid == last_chunk || tid == last_chunk + 1) {
        const int off = (tid - last_chunk) * 16;
        int run = exclc;
#pragma unroll
        for (int j = 0; j < 16; ++j) {
            int v = run;
            run += vals[j];
            v = v > (LZ_N - 1) ? (LZ_N - 1) : v;
            sh_idx[1 + off + j] = v;
            if (t0 == 0 && off == 0 && j == 0) sh_idx[0] = v;  // row 0: unused (c=1)
        }
    }
    if (t0 > 0 && tid == last_chunk - 1) {
        int v = incl - vals[15];          // excl cumsum at base-1
        v = v > (LZ_N - 1) ? (LZ_N - 1) : v;
        sh_idx[0] = v;
    }
    if (tid < ROWS_PER_BLK) {
        const int row = base + tid;
        sh_p[tid] = ((row & (T_N - 1)) == 0) ? 1.0f : p[row];
    }
    __syncthreads();

    // --- gather + smooth + nontemporal store: branch-free main loop ---
    const float* zb = z + (size_t)batch * LZ_N * D_N;
    fx4 v_prev = ((const fx4*)(zb + (size_t)sh_idx[0] * D_N))[tid];

    fx4* outp = (fx4*)out + (size_t)base * (D_N / 4) + tid;

#pragma unroll 8
    for (int j = 0; j < ROWS_PER_BLK; ++j) {
        // unconditional load: repeated rows hit L1; addresses all known after
        // the preamble -> loads pipeline independently.
        fx4 v0 = ((const fx4*)(zb + (size_t)sh_idx[j + 1] * D_N))[tid];
        const float c  = sh_p[j];
        const float om = 1.0f - c;
        fx4 r = c * v0 + om * v_prev;
        __builtin_nontemporal_store(r, outp + (size_t)j * (D_N / 4));
        v_prev = v0;
    }
}

// ---------------------------------------------------------------------------
extern "C" void kernel_launch(void* const* d_in, const int* in_sizes, int n_in,
                              void* d_out, int out_size, void* d_ws, size_t ws_size,
                              hipStream_t stream) {
    const float* z = (const float*)d_in[0];   // (B, LZ, D) f32
    const float* p = (const float*)d_in[1];   // (B, T)     f32
    const int*   b = (const int*)d_in[2];     // (B, T)     i32
    // d_in[3] = original_len (unused; == T)

    float* out = (float*)d_out;               // (B, T, D) f32

    fused_kernel<<<NBLK, 256, 0, stream>>>(z, p, b, out);
}

// Round 7
// 31.093 us; speedup vs baseline: 1.0274x; 1.0274x over previous
//
#include <hip/hip_runtime.h>

// Problem constants (from reference): B=8, T=4096, LZ=1024, D=1024
#define B_N   8
#define T_N   4096
#define LZ_N  1024
#define D_N   1024
#define ROWS_TOTAL (B_N * T_N)            // 32768
#define NBLK  2048                        // blocks (divisible by 8 for XCD swizzle)
#define ROWS_PER_BLK (ROWS_TOTAL / NBLK)  // 16 contiguous rows per block

typedef float fx4 __attribute__((ext_vector_type(4)));

// ---------------------------------------------------------------------------
// Fused kernel: each block handles 16 contiguous output rows [base, base+16).
// Preamble: block recomputes the exclusive cumsum of b[batch][0..base+16)
//   itself (<=16 ints/thread, wave-shfl scan) and stashes the 17 needed
//   clipped idx values + 16 p coefs in LDS. b is 16KB/batch -> L2-resident.
// Main phase: STAGED — all 17 z-row loads issued first (17 outstanding
//   loads/thread, repeats are L1 hits), then 16 FMA + nontemporal stores
//   back-to-back: one read burst, one write burst per block.
// XCD-bijective swizzle: each XCD covers exactly one batch -> z working set
//   per XCD = 4MB = its private L2.
// ---------------------------------------------------------------------------
__global__ __launch_bounds__(256) void fused_kernel(const float* __restrict__ z,
                                                    const float* __restrict__ p,
                                                    const int* __restrict__ b,
                                                    float* __restrict__ out) {
    const int bid   = blockIdx.x;
    const int swz   = (bid & 7) * (NBLK / 8) + (bid >> 3);
    const int base  = swz * ROWS_PER_BLK;         // first row of this chunk
    const int batch = base >> 12;                 // T_N = 4096
    const int t0    = base & (T_N - 1);
    const int tid   = threadIdx.x;
    const int lane  = tid & 63;
    const int wid   = tid >> 6;
    const int last_chunk = t0 >> 4;               // chunk index containing base
    const int nchunk     = last_chunk + 1;        // chunks covering [0, base+16)

    const int* bb = b + (size_t)batch * T_N;

    // --- per-thread chunk load + sum (only threads < nchunk do real work) ---
    int vals[16];
    int lsum = 0;
    if (tid < nchunk) {
        const int4* b4 = (const int4*)(bb + tid * 16);
#pragma unroll
        for (int j = 0; j < 4; ++j) {
            int4 v = b4[j];
            vals[4 * j + 0] = v.x;
            vals[4 * j + 1] = v.y;
            vals[4 * j + 2] = v.z;
            vals[4 * j + 3] = v.w;
        }
#pragma unroll
        for (int j = 0; j < 16; ++j) lsum += vals[j];
    }

    // --- inclusive scan over the 256 per-thread sums: shfl within wave, then
    //     combine the 4 wave totals once through LDS ---
    int s = lsum;
#pragma unroll
    for (int off = 1; off < 64; off <<= 1) {
        int n = __shfl_up(s, off, 64);
        if (lane >= off) s += n;
    }
    __shared__ int   wsum[4];
    __shared__ int   sh_idx[ROWS_PER_BLK + 1];
    __shared__ float sh_p[ROWS_PER_BLK];
    if (lane == 63) wsum[wid] = s;
    __syncthreads();
    int wbase = 0;
#pragma unroll
    for (int w = 0; w < 3; ++w) if (w < wid) wbase += wsum[w];
    const int incl  = s + wbase;    // inclusive cumsum of chunk sums through tid
    const int exclc = incl - lsum;  // exclusive cumsum at this chunk's start

    // --- owner thread emits idx[base..base+15]; neighbor emits idx[base-1] ---
    if (tid == last_chunk) {
        int run = exclc;
        int first = -1;
#pragma unroll
        for (int j = 0; j < 16; ++j) {
            int v = run;
            run += vals[j];
            v = v > (LZ_N - 1) ? (LZ_N - 1) : v;
            if (j == 0) first = v;
            sh_idx[1 + j] = v;
        }
        if (t0 == 0) sh_idx[0] = first;   // row 0: prev value unused (c=1)
    }
    if (t0 > 0 && tid == last_chunk - 1) {
        int v = incl - vals[15];          // excl cumsum at base-1
        v = v > (LZ_N - 1) ? (LZ_N - 1) : v;
        sh_idx[0] = v;
    }
    if (tid < ROWS_PER_BLK) {
        const int row = base + tid;
        sh_p[tid] = ((row & (T_N - 1)) == 0) ? 1.0f : p[row];
    }
    __syncthreads();

    // --- staged gather: issue all 17 loads first (repeats hit L1) ---
    const float* zb = z + (size_t)batch * LZ_N * D_N;
    fx4 v[ROWS_PER_BLK + 1];
#pragma unroll
    for (int j = 0; j <= ROWS_PER_BLK; ++j) {
        v[j] = ((const fx4*)(zb + (size_t)sh_idx[j] * D_N))[tid];
    }

    // --- smooth + nontemporal store: one write burst ---
    fx4* outp = (fx4*)out + (size_t)base * (D_N / 4) + tid;
#pragma unroll
    for (int j = 0; j < ROWS_PER_BLK; ++j) {
        const float c  = sh_p[j];
        const float om = 1.0f - c;
        fx4 r = c * v[j + 1] + om * v[j];
        __builtin_nontemporal_store(r, outp + (size_t)j * (D_N / 4));
    }
}

// ---------------------------------------------------------------------------
extern "C" void kernel_launch(void* const* d_in, const int* in_sizes, int n_in,
                              void* d_out, int out_size, void* d_ws, size_t ws_size,
                              hipStream_t stream) {
    const float* z = (const float*)d_in[0];   // (B, LZ, D) f32
    const float* p = (const float*)d_in[1];   // (B, T)     f32
    const int*   b = (const int*)d_in[2];     // (B, T)     i32
    // d_in[3] = original_len (unused; == T)

    float* out = (float*)d_out;               // (B, T, D) f32

    fused_kernel<<<NBLK, 256, 0, stream>>>(z, p, b, out);
}